// Round 14
// baseline (731.995 us; speedup 1.0000x reference)
//
#include <hip/hip_runtime.h>
#include <stdint.h>

#define BATCH 8
#define NPTS 8192
#define NGRP 512
#define GSZ 32
#define NWORK 120   // worker blocks 8..127 (fewer spinners: power + L2 calm)
#define CHUNK 16    // fps->worker publish granularity (steps)
typedef unsigned long long u64;
typedef float vf2 __attribute__((ext_vector_type(2)));

// ((dx*dx + dy*dy) + dz*dz), sequential, round-to-nearest, NO fma contraction.
__device__ __forceinline__ float sq3(float dx, float dy, float dz) {
    return __fadd_rn(__fadd_rn(__fmul_rn(dx, dx), __fmul_rn(dy, dy)), __fmul_rn(dz, dz));
}

// ---- DPP wave-64 reduction steps (VALU pipe, no DS ops) ----
template <int C>
__device__ __forceinline__ float dpp_max_f32_step(float v) {
    const int t = __builtin_amdgcn_update_dpp(__float_as_int(v), __float_as_int(v),
                                              C, 0xF, 0xF, false);
    return fmaxf(v, __int_as_float(t));
}
template <int C>
__device__ __forceinline__ unsigned dpp_min_u32_step(unsigned v) {
    const unsigned t = (unsigned)__builtin_amdgcn_update_dpp((int)v, (int)v,
                                                             C, 0xF, 0xF, false);
    return v < t ? v : t;
}
__device__ __forceinline__ float wave_max_f32(float v) {
    v = dpp_max_f32_step<0x111>(v);
    v = dpp_max_f32_step<0x112>(v);
    v = dpp_max_f32_step<0x114>(v);
    v = dpp_max_f32_step<0x118>(v);
    v = dpp_max_f32_step<0x142>(v);
    v = dpp_max_f32_step<0x143>(v);
    return __int_as_float(__builtin_amdgcn_readlane(__float_as_int(v), 63));
}
__device__ __forceinline__ unsigned wave_min_u32(unsigned v) {
    v = dpp_min_u32_step<0x111>(v);
    v = dpp_min_u32_step<0x112>(v);
    v = dpp_min_u32_step<0x114>(v);
    v = dpp_min_u32_step<0x118>(v);
    v = dpp_min_u32_step<0x142>(v);
    v = dpp_min_u32_step<0x143>(v);
    return (unsigned)__builtin_amdgcn_readlane((int)v, 63);
}

__global__ void zero_rc(unsigned* __restrict__ rc) {
    if (threadIdx.x < BATCH) rc[threadIdx.x] = 0;
}

// ---------------------------------------------------------------------------
// Fused persistent kernel, grid = 128 blocks x 512 threads, 137 KB LDS =>
// 1 block/CU, all co-resident by capacity (128 <= 256 CUs). fps blocks never
// wait on workers; workers wait only on fps progress => deadlock-free.
//   blocks 0..7   : FPS batch b (R11 structure, byte-identical arithmetic).
//                   Publish: at k%16==0, threads tid<48 store chunk [k-16,k)
//                   (one relaxed agent u32 each, from LDS cl — all pre-barrier
//                   values); tid0 releases rc[b]=k-16 (that chunk's stores
//                   were drained by the 15 intervening barrier vmcnt(0)s).
//                   Final chunk + rc=512 after the loop, behind barriers.
//   blocks 8..127 : KNN workers; rows t=(wid-8)+i*120, (b,g)=(t&7,t>>3).
//                   tid0 acquire-spins rc[b]>g throttled by s_sleep(64)
//                   (~4096 cyc), then R13's proven 512-thread knn row body.
// ---------------------------------------------------------------------------
__global__ __launch_bounds__(512) void fused_kernel(const float* __restrict__ xyz,
                                                    float* __restrict__ centers,
                                                    float* __restrict__ neigh,
                                                    float* __restrict__ neigh_n,
                                                    unsigned* __restrict__ rc,
                                                    unsigned* __restrict__ cp) {
    __shared__ float4 P4[NPTS];     // fps role: 128 KB coord table
    __shared__ double pkey[2][8];   // fps role
    __shared__ float cl[NGRP * 3];  // fps role: centers staging
    __shared__ u64 rk[2][8];        // worker role
    __shared__ int sel[GSZ];        // worker role

    const int wid = blockIdx.x;
    const int tid = threadIdx.x;
    const int lane = tid & 63;
    const int wv = tid >> 6;  // 0..7

    if (wid < BATCH) {
        // ================= FPS role =================
        const int b = wid;
        vf2 px[8], py[8], pz[8], d2[8];
        const float* base = xyz + (size_t)b * NPTS * 6;

#pragma unroll
        for (int i = 0; i < 16; ++i) {
            const int p = i * 512 + tid;
            const float4 v4 = *reinterpret_cast<const float4*>(base + (size_t)p * 6);
            px[i >> 1][i & 1] = v4.x; py[i >> 1][i & 1] = v4.y; pz[i >> 1][i & 1] = v4.z;
            d2[i >> 1][i & 1] = __int_as_float(0x7f800000);  // +inf
            P4[p] = make_float4(v4.x, v4.y, v4.z, 0.0f);
        }
        float Bx = base[0], By = base[1], Bz = base[2];
        if (tid == 0) { cl[0] = Bx; cl[1] = By; cl[2] = Bz; }
        __syncthreads();  // P4 ready

        for (int k = 1; k < NGRP; ++k) {
            // packed distance update, contraction OFF (exact RN mul/add)
            {
#pragma clang fp contract(off)
                const vf2 bx2 = {Bx, Bx}, by2 = {By, By}, bz2 = {Bz, Bz};
#pragma unroll
                for (int j = 0; j < 8; ++j) {
                    const vf2 dx = px[j] - bx2;
                    const vf2 dy = py[j] - by2;
                    const vf2 dz = pz[j] - bz2;
                    const vf2 mx2 = dx * dx;
                    const vf2 my2 = dy * dy;
                    const vf2 mz2 = dz * dz;
                    const vf2 s = (mx2 + my2) + mz2;
                    d2[j] = __builtin_elementwise_min(d2[j], s);
                }
            }
            // packed max tree
            vf2 mv = d2[0];
#pragma unroll
            for (int j = 1; j < 8; ++j) mv = __builtin_elementwise_max(mv, d2[j]);
            const float mx = fmaxf(mv[0], mv[1]);
            const float wmx = wave_max_f32(mx);
            int wi = 0;
#pragma unroll
            for (int i = 15; i >= 1; --i) {
                wi = (d2[i >> 1][i & 1] == mx) ? i : wi;  // lowest matching slot
            }
            unsigned widx_w;
            const u64 bal = __ballot(mx == wmx);
            if (__popcll(bal) == 1) {
                const int L = __ffsll(bal) - 1;
                widx_w = (unsigned)(__builtin_amdgcn_readlane(wi, L) * 512 + (wv * 64 + L));
            } else {
                const unsigned cand = (mx == wmx) ? (unsigned)(wi * 512 + tid) : 0xFFFFFFFFu;
                widx_w = wave_min_u32(cand);
            }

            const int buf = k & 1;
            if ((tid & 63) == 0) {
                pkey[buf][wv] = __hiloint2double(__float_as_int(wmx), 8191 - (int)widx_w);
            }
            __syncthreads();  // LDS-only drain

            // ---- publish (amortized, parallel, deferred release) ----
            if ((k & (CHUNK - 1)) == 0) {
                if (tid == 0 && k >= 2 * CHUNK) {
                    // previous chunk's stores drained by 15 intervening barriers
                    __hip_atomic_store(&rc[b], (unsigned)(k - CHUNK),
                                       __ATOMIC_RELEASE, __HIP_MEMORY_SCOPE_AGENT);
                }
                if (tid < 3 * CHUNK) {  // 48 threads, one component each
                    const int j = (k - CHUNK) * 3 + tid;  // cl[j] pre-barrier value
                    __hip_atomic_store(&cp[b * NGRP * 3 + j], __float_as_uint(cl[j]),
                                       __ATOMIC_RELAXED, __HIP_MEMORY_SCOPE_AGENT);
                }
            }

            const double2* pp = reinterpret_cast<const double2*>(&pkey[buf][0]);
            const double2 a = pp[0], c = pp[1], e = pp[2], f = pp[3];
            const double g = fmax(fmax(fmax(a.x, a.y), fmax(c.x, c.y)),
                                  fmax(fmax(e.x, e.y), fmax(f.x, f.y)));
            const int widx = 8191 - __double2loint(g);
            const float4 c4 = P4[widx];  // broadcast ds_read_b128
            Bx = c4.x; By = c4.y; Bz = c4.z;

            if (tid == 0) { cl[k * 3 + 0] = Bx; cl[k * 3 + 1] = By; cl[k * 3 + 2] = Bz; }
        }

        __syncthreads();
        float* cg = centers + (size_t)b * NGRP * 3;
        for (int t2 = tid; t2 < NGRP * 3; t2 += 512) cg[t2] = cl[t2];
        if (tid < 3 * CHUNK) {  // final chunk [496,512)
            const int j = (NGRP - CHUNK) * 3 + tid;
            __hip_atomic_store(&cp[b * NGRP * 3 + j], __float_as_uint(cl[j]),
                               __ATOMIC_RELAXED, __HIP_MEMORY_SCOPE_AGENT);
        }
        __syncthreads();  // drains all the above stores (vmcnt(0) per thread)
        if (tid == 0) {
            __hip_atomic_store(&rc[b], (unsigned)NGRP,
                               __ATOMIC_RELEASE, __HIP_MEMORY_SCOPE_AGENT);
        }

    } else {
        // ================= KNN worker role =================
        for (int t = wid - BATCH; t < BATCH * NGRP; t += NWORK) {
            const int b = t & 7, g = t >> 3;
            if (tid == 0) {
                while (__hip_atomic_load(&rc[b], __ATOMIC_ACQUIRE,
                                         __HIP_MEMORY_SCOPE_AGENT) <= (unsigned)g) {
                    __builtin_amdgcn_s_sleep(64);  // ~4096 cyc: calm spin
                }
            }
            __syncthreads();  // center g available agent-wide

            const int gi = (b * NGRP + g) * 3;
            const float cx = __uint_as_float(__hip_atomic_load(
                &cp[gi + 0], __ATOMIC_RELAXED, __HIP_MEMORY_SCOPE_AGENT));
            const float cy = __uint_as_float(__hip_atomic_load(
                &cp[gi + 1], __ATOMIC_RELAXED, __HIP_MEMORY_SCOPE_AGENT));
            const float cz = __uint_as_float(__hip_atomic_load(
                &cp[gi + 2], __ATOMIC_RELAXED, __HIP_MEMORY_SCOPE_AGENT));
            const float c2 = sq3(cx, cy, cz);

            const float* base = xyz + (size_t)b * NPTS * 6;
            u64 key[16];
#pragma unroll
            for (int i = 0; i < 16; ++i) {
                const int p = i * 512 + tid;
                const float4 v4 = *reinterpret_cast<const float4*>(base + (size_t)p * 6);
                const float x = v4.x, y = v4.y, z = v4.z;
                const float x2 = sq3(x, y, z);
                const float dot = __fmaf_rn(cz, z, __fmaf_rn(cy, y, __fmul_rn(cx, x)));
                const float dd = __fadd_rn(__fsub_rn(c2, __fmul_rn(2.0f, dot)), x2);
                unsigned u = __float_as_uint(dd);
                u ^= (unsigned)(((int)u >> 31)) | 0x80000000u;
                key[i] = ((u64)u << 32) | (unsigned)p;
            }

            u64 lm = ~0ULL, lm2v = ~0ULL;
#pragma unroll
            for (int i = 0; i < 16; ++i) {
                const u64 kk = key[i];
                const bool a = kk < lm;
                const bool b2 = kk < lm2v;
                lm2v = a ? lm : (b2 ? kk : lm2v);
                lm = a ? kk : lm;
            }

            for (int r = 0; r < GSZ; ++r) {
                const unsigned hi = (unsigned)(lm >> 32);
                const unsigned minhi = wave_min_u32(hi);
                unsigned minlo;
                const u64 bal = __ballot(hi == minhi);
                if (__popcll(bal) == 1) {
                    const int L = __ffsll(bal) - 1;
                    minlo = (unsigned)__builtin_amdgcn_readlane((int)(unsigned)lm, L);
                } else {
                    const unsigned cand = (hi == minhi) ? (unsigned)lm : 0xFFFFFFFFu;
                    minlo = wave_min_u32(cand);
                }
                const u64 mk = ((u64)minhi << 32) | minlo;

                const int rb = r & 1;
                if (lane == 0) rk[rb][wv] = mk;
                __syncthreads();
                const ulonglong2* rp = reinterpret_cast<const ulonglong2*>(&rk[rb][0]);
                const ulonglong2 r0 = rp[0], r1 = rp[1], r2 = rp[2], r3 = rp[3];
                const u64 m0 = r0.x < r0.y ? r0.x : r0.y;
                const u64 m1 = r1.x < r1.y ? r1.x : r1.y;
                const u64 m2 = r2.x < r2.y ? r2.x : r2.y;
                const u64 m3 = r3.x < r3.y ? r3.x : r3.y;
                const u64 m01 = m0 < m1 ? m0 : m1;
                const u64 m23 = m2 < m3 ? m2 : m3;
                const u64 gm = m01 < m23 ? m01 : m23;
                if (tid == 0) sel[r] = (int)(unsigned)(gm & 0xffffffffu);
                if (lm == gm) {  // unique owner pops
                    if (lm2v != 0ULL) {
                        lm = lm2v;
                    } else {
                        u64 nm = ~0ULL;
#pragma unroll
                        for (int i = 0; i < 16; ++i) {
                            const u64 v = key[i] > gm ? key[i] : ~0ULL;
                            nm = v < nm ? v : nm;
                        }
                        lm = nm;
                    }
                    lm2v = 0ULL;  // invalidate (0 never a valid key)
                }
            }
            __syncthreads();

            if (tid < GSZ) {
                const int idx = sel[tid];
                const float* q = base + (size_t)idx * 6;
                const float4 a4 = *reinterpret_cast<const float4*>(q);
                const float2 b2v = *reinterpret_cast<const float2*>(q + 4);
                const int row = b * NGRP + g;
                const size_t o = ((size_t)row * GSZ + tid) * 3;
                neigh[o + 0] = __fsub_rn(a4.x, cx);
                neigh[o + 1] = __fsub_rn(a4.y, cy);
                neigh[o + 2] = __fsub_rn(a4.z, cz);
                neigh_n[o + 0] = a4.w;
                neigh_n[o + 1] = b2v.x;
                neigh_n[o + 2] = b2v.y;
            }
            // next row's first sel write is behind the row-start barrier
        }
    }
}

extern "C" void kernel_launch(void* const* d_in, const int* in_sizes, int n_in,
                              void* d_out, int out_size, void* d_ws, size_t ws_size,
                              hipStream_t stream) {
    const float* xyz = (const float*)d_in[0];
    float* out = (float*)d_out;
    float* neigh   = out;                                       // [8,512,32,3]
    float* neigh_n = out + (size_t)BATCH * NGRP * GSZ * 3;      // [8,512,32,3]
    float* centers = out + (size_t)2 * BATCH * NGRP * GSZ * 3;  // [8,512,3]

    // d_ws: rc[8] @0 (1 KB pad), cp AoS center plane @1024 (48 KB)
    unsigned* rc = (unsigned*)d_ws;
    unsigned* cp = (unsigned*)((char*)d_ws + 1024);

    zero_rc<<<1, 64, 0, stream>>>(rc);
    fused_kernel<<<BATCH + NWORK, 512, 0, stream>>>(xyz, centers, neigh, neigh_n,
                                                    rc, cp);
}

// Round 15
// 511.843 us; speedup vs baseline: 1.4301x; 1.4301x over previous
//
#include <hip/hip_runtime.h>
#include <stdint.h>

#define BATCH 8
#define NPTS 8192
#define NGRP 512
#define GSZ 32

typedef float vf2 __attribute__((ext_vector_type(2)));

// ((dx*dx + dy*dy) + dz*dz), sequential, round-to-nearest, NO fma contraction —
// matches XLA-CPU strict elementwise square + sequential axis-sum.
__device__ __forceinline__ float sq3(float dx, float dy, float dz) {
    return __fadd_rn(__fadd_rn(__fmul_rn(dx, dx), __fmul_rn(dy, dy)), __fmul_rn(dz, dz));
}

// ---- DPP wave-64 reduction steps (VALU pipe, no DS ops) ----
template <int C>
__device__ __forceinline__ float dpp_max_f32_step(float v) {
    const int t = __builtin_amdgcn_update_dpp(__float_as_int(v), __float_as_int(v),
                                              C, 0xF, 0xF, false);
    return fmaxf(v, __int_as_float(t));
}
template <int C>
__device__ __forceinline__ unsigned dpp_min_u32_step(unsigned v) {
    const unsigned t = (unsigned)__builtin_amdgcn_update_dpp((int)v, (int)v,
                                                             C, 0xF, 0xF, false);
    return v < t ? v : t;
}
__device__ __forceinline__ float wave_max_f32(float v) {
    v = dpp_max_f32_step<0x111>(v);
    v = dpp_max_f32_step<0x112>(v);
    v = dpp_max_f32_step<0x114>(v);
    v = dpp_max_f32_step<0x118>(v);
    v = dpp_max_f32_step<0x142>(v);
    v = dpp_max_f32_step<0x143>(v);
    return __int_as_float(__builtin_amdgcn_readlane(__float_as_int(v), 63));
}
__device__ __forceinline__ unsigned wave_min_u32(unsigned v) {
    v = dpp_min_u32_step<0x111>(v);
    v = dpp_min_u32_step<0x112>(v);
    v = dpp_min_u32_step<0x114>(v);
    v = dpp_min_u32_step<0x118>(v);
    v = dpp_min_u32_step<0x142>(v);
    v = dpp_min_u32_step<0x143>(v);
    return (unsigned)__builtin_amdgcn_readlane((int)v, 63);
}

// ---------------------------------------------------------------------------
// FPS: one block per batch, 512 threads, 16 points/thread in registers.
// R11 structure (best measured): float4 init loads, packed-f32 update with
// contract(off), packed max tree, DPP wave reduce + ballot fast path, P4
// coord table in LDS (128 KB) for broadcast winner fetch, LDS-staged centers.
// Exact: FP arithmetic byte-identical to reference chain; argmax exact with
// lowest-index ties at every level (== jnp.argmax).
// ---------------------------------------------------------------------------
__global__ __launch_bounds__(512) void fps_kernel(const float* __restrict__ xyz,
                                                  float* __restrict__ centers) {
    const int b = blockIdx.x;
    const int tid = threadIdx.x;
    const int wv = tid >> 6;  // 0..7

    __shared__ float4 P4[NPTS];      // 128 KB coord table
    __shared__ double pkey[2][8];
    __shared__ float cl[NGRP * 3];   // 6 KB centers staging

    vf2 px[8], py[8], pz[8], d2[8];
    const float* base = xyz + (size_t)b * NPTS * 6;

#pragma unroll
    for (int i = 0; i < 16; ++i) {
        const int p = i * 512 + tid;
        // one dwordx4 @ p*24 (dword-aligned; covers x,y,z,+nx) instead of 3 dwords
        const float4 v4 = *reinterpret_cast<const float4*>(base + (size_t)p * 6);
        px[i >> 1][i & 1] = v4.x; py[i >> 1][i & 1] = v4.y; pz[i >> 1][i & 1] = v4.z;
        d2[i >> 1][i & 1] = __int_as_float(0x7f800000);  // +inf
        P4[p] = make_float4(v4.x, v4.y, v4.z, 0.0f);
    }
    float Bx = base[0], By = base[1], Bz = base[2];
    if (tid == 0) { cl[0] = Bx; cl[1] = By; cl[2] = Bz; }
    __syncthreads();  // P4 ready

    for (int k = 1; k < NGRP; ++k) {
        // ---- packed distance update, contraction OFF (exact RN mul/add) ----
        {
#pragma clang fp contract(off)
            const vf2 bx2 = {Bx, Bx}, by2 = {By, By}, bz2 = {Bz, Bz};
#pragma unroll
            for (int j = 0; j < 8; ++j) {
                const vf2 dx = px[j] - bx2;
                const vf2 dy = py[j] - by2;
                const vf2 dz = pz[j] - bz2;
                const vf2 mx2 = dx * dx;
                const vf2 my2 = dy * dy;
                const vf2 mz2 = dz * dz;
                const vf2 s = (mx2 + my2) + mz2;
                d2[j] = __builtin_elementwise_min(d2[j], s);  // v_pk_min_f32
            }
        }
        // ---- packed max tree ----
        vf2 mv = d2[0];
#pragma unroll
        for (int j = 1; j < 8; ++j) mv = __builtin_elementwise_max(mv, d2[j]);
        const float mx = fmaxf(mv[0], mv[1]);
        const float wmx = wave_max_f32(mx);
        // ---- lowest-slot recovery (slot i -> global idx i*512+tid, monotone) ----
        int wi = 0;
#pragma unroll
        for (int i = 15; i >= 1; --i) {
            wi = (d2[i >> 1][i & 1] == mx) ? i : wi;
        }
        // ---- wave winning index: ballot fast path, DPP-min fallback on ties ----
        unsigned widx_w;
        const unsigned long long bal = __ballot(mx == wmx);
        if (__popcll(bal) == 1) {  // wave-uniform branch
            const int L = __ffsll(bal) - 1;
            widx_w = (unsigned)(__builtin_amdgcn_readlane(wi, L) * 512 + (wv * 64 + L));
        } else {
            const unsigned cand = (mx == wmx) ? (unsigned)(wi * 512 + tid) : 0xFFFFFFFFu;
            widx_w = wave_min_u32(cand);
        }

        const int buf = k & 1;
        if ((tid & 63) == 0) {
            pkey[buf][wv] = __hiloint2double(__float_as_int(wmx), 8191 - (int)widx_w);
        }
        __syncthreads();  // LDS-only drain

        // ---- 7-fmax tree over 8 wave slots (4 x ds_read_b128) ----
        const double2* pp = reinterpret_cast<const double2*>(&pkey[buf][0]);
        const double2 a = pp[0], c = pp[1], e = pp[2], f = pp[3];
        const double g = fmax(fmax(fmax(a.x, a.y), fmax(c.x, c.y)),
                              fmax(fmax(e.x, e.y), fmax(f.x, f.y)));
        const int widx = 8191 - __double2loint(g);
        const float4 c4 = P4[widx];  // broadcast ds_read_b128
        Bx = c4.x; By = c4.y; Bz = c4.z;

        if (tid == 0) { cl[k * 3 + 0] = Bx; cl[k * 3 + 1] = By; cl[k * 3 + 2] = Bz; }
    }

    __syncthreads();
    float* cg = centers + (size_t)b * NGRP * 3;
    for (int t = tid; t < NGRP * 3; t += 512) cg[t] = cl[t];
}

// ---------------------------------------------------------------------------
// KNN + gather: one block (256 threads) per (batch, group) row.
// FP math byte-identical to the reference lowering (FMA-chain dot). Selection:
// lazy 2-deep cached min, ballot shortcut for the lo-word chain, DPP reduces.
// ---------------------------------------------------------------------------
__global__ __launch_bounds__(256) void knn_kernel(const float* __restrict__ xyz,
                                                  const float* __restrict__ centers,
                                                  float* __restrict__ neigh,
                                                  float* __restrict__ neigh_n) {
    const int row = blockIdx.x;   // b*NGRP + g
    const int b = row >> 9;
    const int tid = threadIdx.x;
    const int lane = tid & 63;
    const int wv = tid >> 6;  // 0..3

    __shared__ unsigned long long rk[2][4];
    __shared__ int sel[GSZ];

    const float* cptr = centers + (size_t)row * 3;
    const float cx = cptr[0], cy = cptr[1], cz = cptr[2];
    const float c2 = sq3(cx, cy, cz);

    const float* base = xyz + (size_t)b * NPTS * 6;
    unsigned long long key[32];
#pragma unroll
    for (int i = 0; i < 32; ++i) {
        const int p = i * 256 + tid;
        const float4 v4 = *reinterpret_cast<const float4*>(base + (size_t)p * 6);
        const float x = v4.x, y = v4.y, z = v4.z;
        const float x2 = sq3(x, y, z);
        // GEMM-style FMA accumulation over k = x,y,z
        const float dot = __fmaf_rn(cz, z, __fmaf_rn(cy, y, __fmul_rn(cx, x)));
        const float d2 = __fadd_rn(__fsub_rn(c2, __fmul_rn(2.0f, dot)), x2);
        // monotonic float->uint transform
        unsigned u = __float_as_uint(d2);
        u ^= (unsigned)(((int)u >> 31)) | 0x80000000u;
        key[i] = ((unsigned long long)u << 32) | (unsigned)p;
    }

    // 2-deep cached mins over this thread's 32 keys (keys unique, never 0)
    unsigned long long lm = ~0ULL, lm2v = ~0ULL;
#pragma unroll
    for (int i = 0; i < 32; ++i) {
        const unsigned long long kk = key[i];
        const bool a = kk < lm;
        const bool b2 = kk < lm2v;
        lm2v = a ? lm : (b2 ? kk : lm2v);
        lm = a ? kk : lm;
    }

    for (int r = 0; r < GSZ; ++r) {
        // ---- wave u64 min: hi chain + ballot shortcut for lo ----
        const unsigned hi = (unsigned)(lm >> 32);
        const unsigned minhi = wave_min_u32(hi);
        unsigned minlo;
        const unsigned long long bal = __ballot(hi == minhi);
        if (__popcll(bal) == 1) {  // wave-uniform branch
            const int L = __ffsll(bal) - 1;
            minlo = (unsigned)__builtin_amdgcn_readlane((int)(unsigned)lm, L);
        } else {
            const unsigned cand = (hi == minhi) ? (unsigned)lm : 0xFFFFFFFFu;
            minlo = wave_min_u32(cand);
        }
        const unsigned long long mk = ((unsigned long long)minhi << 32) | minlo;

        const int rb = r & 1;
        if (lane == 0) rk[rb][wv] = mk;
        __syncthreads();
        const ulonglong2* rp = reinterpret_cast<const ulonglong2*>(&rk[rb][0]);
        const ulonglong2 r0 = rp[0], r1 = rp[1];
        const unsigned long long g01 = r0.x < r0.y ? r0.x : r0.y;
        const unsigned long long g23 = r1.x < r1.y ? r1.x : r1.y;
        const unsigned long long gm = g01 < g23 ? g01 : g23;
        if (tid == 0) sel[r] = (int)(unsigned)(gm & 0xffffffffu);
        if (lm == gm) {  // unique owner pops
            if (lm2v != 0ULL) {
                lm = lm2v;
            } else {
                unsigned long long nm = ~0ULL;
#pragma unroll
                for (int i = 0; i < 32; ++i) {
                    const unsigned long long v = key[i] > gm ? key[i] : ~0ULL;
                    nm = v < nm ? v : nm;
                }
                lm = nm;
            }
            lm2v = 0ULL;  // invalidate (0 is never a valid key)
        }
    }
    __syncthreads();

    if (tid < GSZ) {
        const int idx = sel[tid];
        const float* q = base + (size_t)idx * 6;
        const float4 a4 = *reinterpret_cast<const float4*>(q);      // x,y,z,nx
        const float2 b2v = *reinterpret_cast<const float2*>(q + 4); // ny,nz
        const size_t o = ((size_t)row * GSZ + tid) * 3;
        neigh[o + 0] = __fsub_rn(a4.x, cx);
        neigh[o + 1] = __fsub_rn(a4.y, cy);
        neigh[o + 2] = __fsub_rn(a4.z, cz);
        neigh_n[o + 0] = a4.w;
        neigh_n[o + 1] = b2v.x;
        neigh_n[o + 2] = b2v.y;
    }
}

extern "C" void kernel_launch(void* const* d_in, const int* in_sizes, int n_in,
                              void* d_out, int out_size, void* d_ws, size_t ws_size,
                              hipStream_t stream) {
    const float* xyz = (const float*)d_in[0];
    float* out = (float*)d_out;
    float* neigh   = out;                                   // [8,512,32,3]
    float* neigh_n = out + (size_t)BATCH * NGRP * GSZ * 3;  // [8,512,32,3]
    float* centers = out + (size_t)2 * BATCH * NGRP * GSZ * 3;  // [8,512,3]

    fps_kernel<<<BATCH, 512, 0, stream>>>(xyz, centers);
    knn_kernel<<<BATCH * NGRP, 256, 0, stream>>>(xyz, centers, neigh, neigh_n);
}